// Round 10
// baseline (173.590 us; speedup 1.0000x reference)
//
#include <hip/hip_runtime.h>
#include <hip/hip_bf16.h>

typedef __attribute__((ext_vector_type(4))) float f32x4;
typedef __attribute__((ext_vector_type(8))) short bf16x8;

#define HW    16384   // 128*128
#define CDIM  256

__device__ __forceinline__ unsigned short f2bf(float x) {
    union { float f; unsigned u; } c; c.f = x;
    unsigned r = c.u + 0x7fffu + ((c.u >> 16) & 1u);   // RNE
    return (unsigned short)(r >> 16);
}
__device__ __forceinline__ float bf2f(unsigned short u) {
    union { unsigned u; float f; } c; c.u = ((unsigned)u) << 16;
    return c.f;
}

// A/B LDS tile: 128 rows x 64 k bf16, 128B rows.
// byte(row,k) = row*128 + ((k*2) ^ ((row&7)<<4))  -> measured 262K conflicts (R2).
__device__ __forceinline__ int tswz(int row, int kbyte) {
    return row * 128 + (kbyte ^ ((row & 7) << 4));
}

// F2t[pixel][c] = sum_k W1[c,k] * feat[k][pixel]  (bf16 out, channel-last)
// R9 champion verbatim EXCEPT __launch_bounds__(256,2) -> (256,3):
// single-variable occupancy test (R5/R7 showed ~31% occ at arg>=2 with low
// VGPR; w=3 VGPR cap >=168 > 104 used, so no R6-style spill is possible).
// Grid map: b = xcd + 8*n_half + 16*j -> m_tile = xcd*128 + j (R9-proven:
// FETCH 133 -> 68 MB, -8 us bench).
__global__ __launch_bounds__(256, 3) void f2_gemm(
    const float* __restrict__ feat, const float* __restrict__ W1,
    unsigned short* __restrict__ f2t) {
    __shared__ short lds[16384];            // 32KB: A bytes [0,16384), B [16384,32768)
    char* const ldsc = (char*)lds;

    const int t      = threadIdx.x;
    const int b      = blockIdx.x;
    const int m_tile = ((b & 7) << 7) | (b >> 4);   // xcd*128 + j
    const int n_half = (b >> 3) & 1;
    const int m_base = m_tile << 7;
    const float* fb  = feat + (size_t)(m_base >> 14) * CDIM * HW + (m_base & (HW - 1));
    const float* wb  = W1 + (size_t)(n_half * 128) * CDIM;

    const int lane = t & 63;
    const int wid  = t >> 6;
    const int wm   = wid >> 1;           // 2 m-slabs of 64
    const int wn   = wid & 1;            // 2 n-slabs of 64

    const int sm0 = (t >> 3) << 2;       // staging row base 0..124 (A:m, B:c)
    const int kb  = (t & 7) << 3;        // staging k base 0..56 (8 k/thread)

    f32x4 acc[4][4] = {};
    float av[8][4];                      // A raw: [dk][dm]
    float bv[4][8];                      // B raw: [dc][dk]

    auto load_tile = [&](int kk) {
        const float* fk = fb + (size_t)(kk * 64 + kb) * HW + sm0;
#pragma unroll
        for (int dk = 0; dk < 8; ++dk) {
            const float4 v = *reinterpret_cast<const float4*>(fk + (size_t)dk * HW);
            av[dk][0] = v.x; av[dk][1] = v.y; av[dk][2] = v.z; av[dk][3] = v.w;
        }
        const float* wk = wb + (size_t)sm0 * CDIM + kk * 64 + kb;
#pragma unroll
        for (int dc = 0; dc < 4; ++dc) {
            const float4 u = *reinterpret_cast<const float4*>(wk + (size_t)dc * CDIM);
            const float4 w = *reinterpret_cast<const float4*>(wk + (size_t)dc * CDIM + 4);
            bv[dc][0] = u.x; bv[dc][1] = u.y; bv[dc][2] = u.z; bv[dc][3] = u.w;
            bv[dc][4] = w.x; bv[dc][5] = w.y; bv[dc][6] = w.z; bv[dc][7] = w.w;
        }
    };

    auto write_tile = [&]() {
#pragma unroll
        for (int dm = 0; dm < 4; ++dm) {           // A: transpose in regs
            const int row = sm0 + dm;
            bf16x8 w;
#pragma unroll
            for (int dk = 0; dk < 8; ++dk) w[dk] = (short)f2bf(av[dk][dm]);
            *reinterpret_cast<bf16x8*>(ldsc + tswz(row, kb * 2)) = w;
        }
#pragma unroll
        for (int dc = 0; dc < 4; ++dc) {           // B: k already contiguous
            const int row = sm0 + dc;
            bf16x8 w;
#pragma unroll
            for (int dk = 0; dk < 8; ++dk) w[dk] = (short)f2bf(bv[dc][dk]);
            *reinterpret_cast<bf16x8*>(ldsc + 16384 + tswz(row, kb * 2)) = w;
        }
    };

    auto compute = [&]() {
#pragma unroll
        for (int ks = 0; ks < 2; ++ks) {
            const int kb2 = ks * 64 + ((lane >> 4) << 4);   // byte offset of k*2
            bf16x8 af[4], bfr[4];
#pragma unroll
            for (int mi = 0; mi < 4; ++mi) {
                const int row = wm * 64 + mi * 16 + (lane & 15);
                af[mi] = *reinterpret_cast<const bf16x8*>(ldsc + tswz(row, kb2));
            }
#pragma unroll
            for (int ni = 0; ni < 4; ++ni) {
                const int c = wn * 64 + ni * 16 + (lane & 15);
                bfr[ni] = *reinterpret_cast<const bf16x8*>(ldsc + 16384 + tswz(c, kb2));
            }
#pragma unroll
            for (int mi = 0; mi < 4; ++mi)
#pragma unroll
                for (int ni = 0; ni < 4; ++ni)
                    acc[mi][ni] = __builtin_amdgcn_mfma_f32_16x16x32_bf16(
                        af[mi], bfr[ni], acc[mi][ni], 0, 0, 0);
        }
    };

    // prologue
    load_tile(0);
    write_tile();
    __syncthreads();
    // main loop: issue k+1 loads before compute(k), convert/write after
    for (int kk = 0; kk < 4; ++kk) {
        if (kk < 3) load_tile(kk + 1);
        compute();
        __syncthreads();
        if (kk < 3) { write_tile(); __syncthreads(); }
    }

    // ---- epilogue: acc -> bf16 -> LDS (swizzled) -> coalesced dwordx4 stores
#pragma unroll
    for (int mi = 0; mi < 4; ++mi)
#pragma unroll
        for (int ni = 0; ni < 4; ++ni) {
            const int c2 = (wn * 64 + ni * 16 + (lane & 15)) * 2;
#pragma unroll
            for (int r = 0; r < 4; ++r) {
                const int row = wm * 64 + mi * 16 + ((lane >> 4) << 2) + r;
                *reinterpret_cast<unsigned short*>(
                    ldsc + row * 256 + (c2 ^ (((row >> 2) & 3) << 5))) =
                    f2bf(acc[mi][ni][r]);
            }
        }
    __syncthreads();
#pragma unroll
    for (int i = 0; i < 8; ++i) {
        const int row = ((t >> 4) << 3) + i;
        const int cb  = (t & 15) * 16;
        const int4 v = *reinterpret_cast<const int4*>(
            ldsc + row * 256 + (cb ^ (((row >> 2) & 3) << 5)));
        *reinterpret_cast<int4*>((char*)f2t +
            (size_t)(m_base + row) * 512 + n_half * 256 + cb) = v;
    }
}

// 2 sample points per wave: 32 lanes/point, 8 channels/lane (16B bf16x8
// loads). Bilinear-weighted sum of 4 contiguous 512B F2t rows, then
// relu(s+b1).W2 -> 2 scalars; 5-step shfl_xor reduce within the 32-lane
// group; out = batch_edges + d.
__global__ __launch_bounds__(256) void point_kernel(
    const unsigned short* __restrict__ f2t,
    const float* __restrict__ be,
    const float* __restrict__ b1, const float* __restrict__ W2,
    float* __restrict__ out) {
    const int wave = (blockIdx.x << 2) | ((threadIdx.x >> 6) & 3);
    const int lane = threadIdx.x & 63;
    const int p    = (wave << 1) | (lane >> 5);     // 0..65535
    const int l5   = lane & 31;
    const int c0   = l5 << 3;                       // 8 channels per lane

    const float ex = be[p * 2 + 0];
    const float ey = be[p * 2 + 1];
    const float gx = ex * (2.0f / 128.0f) - 1.0f;
    const float gy = ey * (2.0f / 128.0f) - 1.0f;
    const float px = (gx + 1.0f) * 64.0f - 0.5f;
    const float py = (gy + 1.0f) * 64.0f - 0.5f;
    const float x0f = floorf(px), y0f = floorf(py);
    const int   x0 = (int)x0f, y0 = (int)y0f;
    const float wx1 = px - x0f, wy1 = py - y0f;
    const float wx0 = 1.0f - wx1, wy0 = 1.0f - wy1;

    const size_t pix_base = (size_t)(p >> 13) * HW;

    float s[8] = {};
#pragma unroll
    for (int cy = 0; cy < 2; ++cy) {
        const int   yi  = y0 + cy;
        const float wy  = cy ? wy1 : wy0;
        const bool  yin = (yi >= 0) && (yi < 128);
        const int   yc  = min(max(yi, 0), 127);
#pragma unroll
        for (int cx = 0; cx < 2; ++cx) {
            const int   xi  = x0 + cx;
            const float wx  = cx ? wx1 : wx0;
            const bool  xin = (xi >= 0) && (xi < 128);
            const int   xc  = min(max(xi, 0), 127);
            const float w   = wx * wy * (float)(xin && yin);
            const bf16x8 v = *reinterpret_cast<const bf16x8*>(
                &f2t[(pix_base + (size_t)yc * 128 + xc) * 256 + c0]);
#pragma unroll
            for (int j = 0; j < 8; ++j)
                s[j] += w * bf2f((unsigned short)v[j]);
        }
    }
    const float4 bb0 = *reinterpret_cast<const float4*>(&b1[c0]);
    const float4 bb1 = *reinterpret_cast<const float4*>(&b1[c0 + 4]);
    const float4 wa0 = *reinterpret_cast<const float4*>(&W2[c0]);
    const float4 wa1 = *reinterpret_cast<const float4*>(&W2[c0 + 4]);
    const float4 wb0 = *reinterpret_cast<const float4*>(&W2[256 + c0]);
    const float4 wb1 = *reinterpret_cast<const float4*>(&W2[256 + c0 + 4]);
    float bias[8] = {bb0.x, bb0.y, bb0.z, bb0.w, bb1.x, bb1.y, bb1.z, bb1.w};
    float w2a[8]  = {wa0.x, wa0.y, wa0.z, wa0.w, wa1.x, wa1.y, wa1.z, wa1.w};
    float w2b[8]  = {wb0.x, wb0.y, wb0.z, wb0.w, wb1.x, wb1.y, wb1.z, wb1.w};

    float a0 = 0.f, a1 = 0.f;
#pragma unroll
    for (int j = 0; j < 8; ++j) {
        const float h = fmaxf(s[j] + bias[j], 0.f);
        a0 += h * w2a[j];
        a1 += h * w2b[j];
    }
#pragma unroll
    for (int off = 16; off > 0; off >>= 1) {   // stays within 32-lane group
        a0 += __shfl_xor(a0, off);
        a1 += __shfl_xor(a1, off);
    }
    if (l5 == 0) {
        out[p * 2 + 0] = ex + a0;
        out[p * 2 + 1] = ey + a1;
    }
}

extern "C" void kernel_launch(void* const* d_in, const int* in_sizes, int n_in,
                              void* d_out, int out_size, void* d_ws, size_t ws_size,
                              hipStream_t stream) {
    const float* feat = (const float*)d_in[0];
    const float* be   = (const float*)d_in[1];
    const float* W1   = (const float*)d_in[2];
    const float* b1   = (const float*)d_in[3];
    const float* W2   = (const float*)d_in[4];
    float* out = (float*)d_out;
    unsigned short* f2t = (unsigned short*)d_ws;   // 131072*256 bf16 = 64 MiB

    f2_gemm<<<2048, 256, 0, stream>>>(feat, W1, f2t);
    point_kernel<<<8192, 256, 0, stream>>>(f2t, be, b1, W2, out);
}

// Round 11
// 79.542 us; speedup vs baseline: 2.1824x; 2.1824x over previous
//
#include <hip/hip_runtime.h>
#include <hip/hip_bf16.h>

typedef __attribute__((ext_vector_type(4))) float f32x4;
typedef __attribute__((ext_vector_type(8))) short bf16x8;

#define HW    16384   // 128*128
#define CDIM  256

__device__ __forceinline__ unsigned short f2bf(float x) {
    union { float f; unsigned u; } c; c.f = x;
    unsigned r = c.u + 0x7fffu + ((c.u >> 16) & 1u);   // RNE
    return (unsigned short)(r >> 16);
}
__device__ __forceinline__ float bf2f(unsigned short u) {
    union { unsigned u; float f; } c; c.u = ((unsigned)u) << 16;
    return c.f;
}

// A/B LDS tile: 128 rows x 64 k bf16, 128B rows.
// byte(row,k) = row*128 + ((k*2) ^ ((row&7)<<4))  -> measured 262K conflicts (R2).
__device__ __forceinline__ int tswz(int row, int kbyte) {
    return row * 128 + (kbyte ^ ((row & 7) << 4));
}

// F2t[pixel][c] = sum_k W1[c,k] * feat[k][pixel]  (bf16 out, channel-last)
// R9 champion verbatim (79.6 us bench). launch_bounds MUST stay (256,2):
// arg>=3 caps VGPR below the ~104 live regs -> spill (R6: 64 VGPR/944MB,
// R10: 84 VGPR/462MB writes). Grid map: b = xcd + 8*n_half + 16*j ->
// m_tile = xcd*128 + j (R9-proven: FETCH 133 -> 68 MB, -8 us bench).
__global__ __launch_bounds__(256, 2) void f2_gemm(
    const float* __restrict__ feat, const float* __restrict__ W1,
    unsigned short* __restrict__ f2t) {
    __shared__ short lds[16384];            // 32KB: A bytes [0,16384), B [16384,32768)
    char* const ldsc = (char*)lds;

    const int t      = threadIdx.x;
    const int b      = blockIdx.x;
    const int m_tile = ((b & 7) << 7) | (b >> 4);   // xcd*128 + j
    const int n_half = (b >> 3) & 1;
    const int m_base = m_tile << 7;
    const float* fb  = feat + (size_t)(m_base >> 14) * CDIM * HW + (m_base & (HW - 1));
    const float* wb  = W1 + (size_t)(n_half * 128) * CDIM;

    const int lane = t & 63;
    const int wid  = t >> 6;
    const int wm   = wid >> 1;           // 2 m-slabs of 64
    const int wn   = wid & 1;            // 2 n-slabs of 64

    const int sm0 = (t >> 3) << 2;       // staging row base 0..124 (A:m, B:c)
    const int kb  = (t & 7) << 3;        // staging k base 0..56 (8 k/thread)

    f32x4 acc[4][4] = {};
    float av[8][4];                      // A raw: [dk][dm]
    float bv[4][8];                      // B raw: [dc][dk]

    auto load_tile = [&](int kk) {
        const float* fk = fb + (size_t)(kk * 64 + kb) * HW + sm0;
#pragma unroll
        for (int dk = 0; dk < 8; ++dk) {
            const float4 v = *reinterpret_cast<const float4*>(fk + (size_t)dk * HW);
            av[dk][0] = v.x; av[dk][1] = v.y; av[dk][2] = v.z; av[dk][3] = v.w;
        }
        const float* wk = wb + (size_t)sm0 * CDIM + kk * 64 + kb;
#pragma unroll
        for (int dc = 0; dc < 4; ++dc) {
            const float4 u = *reinterpret_cast<const float4*>(wk + (size_t)dc * CDIM);
            const float4 w = *reinterpret_cast<const float4*>(wk + (size_t)dc * CDIM + 4);
            bv[dc][0] = u.x; bv[dc][1] = u.y; bv[dc][2] = u.z; bv[dc][3] = u.w;
            bv[dc][4] = w.x; bv[dc][5] = w.y; bv[dc][6] = w.z; bv[dc][7] = w.w;
        }
    };

    auto write_tile = [&]() {
#pragma unroll
        for (int dm = 0; dm < 4; ++dm) {           // A: transpose in regs
            const int row = sm0 + dm;
            bf16x8 w;
#pragma unroll
            for (int dk = 0; dk < 8; ++dk) w[dk] = (short)f2bf(av[dk][dm]);
            *reinterpret_cast<bf16x8*>(ldsc + tswz(row, kb * 2)) = w;
        }
#pragma unroll
        for (int dc = 0; dc < 4; ++dc) {           // B: k already contiguous
            const int row = sm0 + dc;
            bf16x8 w;
#pragma unroll
            for (int dk = 0; dk < 8; ++dk) w[dk] = (short)f2bf(bv[dc][dk]);
            *reinterpret_cast<bf16x8*>(ldsc + 16384 + tswz(row, kb * 2)) = w;
        }
    };

    auto compute = [&]() {
#pragma unroll
        for (int ks = 0; ks < 2; ++ks) {
            const int kb2 = ks * 64 + ((lane >> 4) << 4);   // byte offset of k*2
            bf16x8 af[4], bfr[4];
#pragma unroll
            for (int mi = 0; mi < 4; ++mi) {
                const int row = wm * 64 + mi * 16 + (lane & 15);
                af[mi] = *reinterpret_cast<const bf16x8*>(ldsc + tswz(row, kb2));
            }
#pragma unroll
            for (int ni = 0; ni < 4; ++ni) {
                const int c = wn * 64 + ni * 16 + (lane & 15);
                bfr[ni] = *reinterpret_cast<const bf16x8*>(ldsc + 16384 + tswz(c, kb2));
            }
#pragma unroll
            for (int mi = 0; mi < 4; ++mi)
#pragma unroll
                for (int ni = 0; ni < 4; ++ni)
                    acc[mi][ni] = __builtin_amdgcn_mfma_f32_16x16x32_bf16(
                        af[mi], bfr[ni], acc[mi][ni], 0, 0, 0);
        }
    };

    // prologue
    load_tile(0);
    write_tile();
    __syncthreads();
    // main loop: issue k+1 loads before compute(k), convert/write after
    for (int kk = 0; kk < 4; ++kk) {
        if (kk < 3) load_tile(kk + 1);
        compute();
        __syncthreads();
        if (kk < 3) { write_tile(); __syncthreads(); }
    }

    // ---- epilogue: acc -> bf16 -> LDS (swizzled) -> coalesced dwordx4 stores
#pragma unroll
    for (int mi = 0; mi < 4; ++mi)
#pragma unroll
        for (int ni = 0; ni < 4; ++ni) {
            const int c2 = (wn * 64 + ni * 16 + (lane & 15)) * 2;
#pragma unroll
            for (int r = 0; r < 4; ++r) {
                const int row = wm * 64 + mi * 16 + ((lane >> 4) << 2) + r;
                *reinterpret_cast<unsigned short*>(
                    ldsc + row * 256 + (c2 ^ (((row >> 2) & 3) << 5))) =
                    f2bf(acc[mi][ni][r]);
            }
        }
    __syncthreads();
#pragma unroll
    for (int i = 0; i < 8; ++i) {
        const int row = ((t >> 4) << 3) + i;
        const int cb  = (t & 15) * 16;
        const int4 v = *reinterpret_cast<const int4*>(
            ldsc + row * 256 + (cb ^ (((row >> 2) & 3) << 5)));
        *reinterpret_cast<int4*>((char*)f2t +
            (size_t)(m_base + row) * 512 + n_half * 256 + cb) = v;
    }
}

// 2 sample points per wave: 32 lanes/point, 8 channels/lane (16B bf16x8
// loads). Bilinear-weighted sum of 4 contiguous 512B F2t rows, then
// relu(s+b1).W2 -> 2 scalars; 5-step shfl_xor reduce within the 32-lane
// group; out = batch_edges + d.
__global__ __launch_bounds__(256) void point_kernel(
    const unsigned short* __restrict__ f2t,
    const float* __restrict__ be,
    const float* __restrict__ b1, const float* __restrict__ W2,
    float* __restrict__ out) {
    const int wave = (blockIdx.x << 2) | ((threadIdx.x >> 6) & 3);
    const int lane = threadIdx.x & 63;
    const int p    = (wave << 1) | (lane >> 5);     // 0..65535
    const int l5   = lane & 31;
    const int c0   = l5 << 3;                       // 8 channels per lane

    const float ex = be[p * 2 + 0];
    const float ey = be[p * 2 + 1];
    const float gx = ex * (2.0f / 128.0f) - 1.0f;
    const float gy = ey * (2.0f / 128.0f) - 1.0f;
    const float px = (gx + 1.0f) * 64.0f - 0.5f;
    const float py = (gy + 1.0f) * 64.0f - 0.5f;
    const float x0f = floorf(px), y0f = floorf(py);
    const int   x0 = (int)x0f, y0 = (int)y0f;
    const float wx1 = px - x0f, wy1 = py - y0f;
    const float wx0 = 1.0f - wx1, wy0 = 1.0f - wy1;

    const size_t pix_base = (size_t)(p >> 13) * HW;

    float s[8] = {};
#pragma unroll
    for (int cy = 0; cy < 2; ++cy) {
        const int   yi  = y0 + cy;
        const float wy  = cy ? wy1 : wy0;
        const bool  yin = (yi >= 0) && (yi < 128);
        const int   yc  = min(max(yi, 0), 127);
#pragma unroll
        for (int cx = 0; cx < 2; ++cx) {
            const int   xi  = x0 + cx;
            const float wx  = cx ? wx1 : wx0;
            const bool  xin = (xi >= 0) && (xi < 128);
            const int   xc  = min(max(xi, 0), 127);
            const float w   = wx * wy * (float)(xin && yin);
            const bf16x8 v = *reinterpret_cast<const bf16x8*>(
                &f2t[(pix_base + (size_t)yc * 128 + xc) * 256 + c0]);
#pragma unroll
            for (int j = 0; j < 8; ++j)
                s[j] += w * bf2f((unsigned short)v[j]);
        }
    }
    const float4 bb0 = *reinterpret_cast<const float4*>(&b1[c0]);
    const float4 bb1 = *reinterpret_cast<const float4*>(&b1[c0 + 4]);
    const float4 wa0 = *reinterpret_cast<const float4*>(&W2[c0]);
    const float4 wa1 = *reinterpret_cast<const float4*>(&W2[c0 + 4]);
    const float4 wb0 = *reinterpret_cast<const float4*>(&W2[256 + c0]);
    const float4 wb1 = *reinterpret_cast<const float4*>(&W2[256 + c0 + 4]);
    float bias[8] = {bb0.x, bb0.y, bb0.z, bb0.w, bb1.x, bb1.y, bb1.z, bb1.w};
    float w2a[8]  = {wa0.x, wa0.y, wa0.z, wa0.w, wa1.x, wa1.y, wa1.z, wa1.w};
    float w2b[8]  = {wb0.x, wb0.y, wb0.z, wb0.w, wb1.x, wb1.y, wb1.z, wb1.w};

    float a0 = 0.f, a1 = 0.f;
#pragma unroll
    for (int j = 0; j < 8; ++j) {
        const float h = fmaxf(s[j] + bias[j], 0.f);
        a0 += h * w2a[j];
        a1 += h * w2b[j];
    }
#pragma unroll
    for (int off = 16; off > 0; off >>= 1) {   // stays within 32-lane group
        a0 += __shfl_xor(a0, off);
        a1 += __shfl_xor(a1, off);
    }
    if (l5 == 0) {
        out[p * 2 + 0] = ex + a0;
        out[p * 2 + 1] = ey + a1;
    }
}

extern "C" void kernel_launch(void* const* d_in, const int* in_sizes, int n_in,
                              void* d_out, int out_size, void* d_ws, size_t ws_size,
                              hipStream_t stream) {
    const float* feat = (const float*)d_in[0];
    const float* be   = (const float*)d_in[1];
    const float* W1   = (const float*)d_in[2];
    const float* b1   = (const float*)d_in[3];
    const float* W2   = (const float*)d_in[4];
    float* out = (float*)d_out;
    unsigned short* f2t = (unsigned short*)d_ws;   // 131072*256 bf16 = 64 MiB

    f2_gemm<<<2048, 256, 0, stream>>>(feat, W1, f2t);
    point_kernel<<<8192, 256, 0, stream>>>(f2t, be, b1, W2, out);
}

// Round 12
// 75.458 us; speedup vs baseline: 2.3005x; 1.0541x over previous
//
#include <hip/hip_runtime.h>
#include <hip/hip_bf16.h>

typedef __attribute__((ext_vector_type(4))) float f32x4;
typedef __attribute__((ext_vector_type(8))) short bf16x8;

#define HW    16384   // 128*128
#define CDIM  256

__device__ __forceinline__ unsigned short f2bf(float x) {
    union { float f; unsigned u; } c; c.f = x;
    unsigned r = c.u + 0x7fffu + ((c.u >> 16) & 1u);   // RNE
    return (unsigned short)(r >> 16);
}
__device__ __forceinline__ float bf2f(unsigned short u) {
    union { unsigned u; float f; } c; c.u = ((unsigned)u) << 16;
    return c.f;
}

// A/B LDS tile: 128 rows x 64 k bf16, 128B rows.
// byte(row,k) = row*128 + ((k*2) ^ ((row&7)<<4))  -> measured 262K conflicts (R2).
__device__ __forceinline__ int tswz(int row, int kbyte) {
    return row * 128 + (kbyte ^ ((row & 7) << 4));
}

// F2t[pixel][c] = sum_k W1[c,k] * feat[k][pixel]  (bf16 out, channel-last)
// R9/R11 champion + DEPTH-2 A-register-prefetch (single change):
//   av[2][8][4]: A(k+2) issued at top of step k -> ~2 compute phases of
//   latency cover for the ~900cy feat loads; B (W1, L2-resident ~200cy)
//   stays depth-1. VGPR ~140 < (256,2) cap 256 -> no spill possible.
// launch_bounds MUST stay (256,2): arg>=3 caps VGPR below live regs ->
// spill (R6: 64 VGPR/944MB, R10: 84 VGPR/462MB writes).
// Grid map: b = xcd + 8*n_half + 16*j -> m_tile = xcd*128 + j (R9-proven:
// FETCH 133 -> 68 MB, -8 us bench).
__global__ __launch_bounds__(256, 2) void f2_gemm(
    const float* __restrict__ feat, const float* __restrict__ W1,
    unsigned short* __restrict__ f2t) {
    __shared__ short lds[16384];            // 32KB: A bytes [0,16384), B [16384,32768)
    char* const ldsc = (char*)lds;

    const int t      = threadIdx.x;
    const int b      = blockIdx.x;
    const int m_tile = ((b & 7) << 7) | (b >> 4);   // xcd*128 + j
    const int n_half = (b >> 3) & 1;
    const int m_base = m_tile << 7;
    const float* fb  = feat + (size_t)(m_base >> 14) * CDIM * HW + (m_base & (HW - 1));
    const float* wb  = W1 + (size_t)(n_half * 128) * CDIM;

    const int lane = t & 63;
    const int wid  = t >> 6;
    const int wm   = wid >> 1;           // 2 m-slabs of 64
    const int wn   = wid & 1;            // 2 n-slabs of 64

    const int sm0 = (t >> 3) << 2;       // staging row base 0..124 (A:m, B:c)
    const int kb  = (t & 7) << 3;        // staging k base 0..56 (8 k/thread)

    f32x4 acc[4][4] = {};
    float av[2][8][4];                   // A raw, DOUBLE reg buffer: [rb][dk][dm]
    float bv[4][8];                      // B raw, depth-1: [dc][dk]

    auto load_a = [&](int kk, int rb) {
        const float* fk = fb + (size_t)(kk * 64 + kb) * HW + sm0;
#pragma unroll
        for (int dk = 0; dk < 8; ++dk) {
            const float4 v = *reinterpret_cast<const float4*>(fk + (size_t)dk * HW);
            av[rb][dk][0] = v.x; av[rb][dk][1] = v.y;
            av[rb][dk][2] = v.z; av[rb][dk][3] = v.w;
        }
    };
    auto load_b = [&](int kk) {
        const float* wk = wb + (size_t)sm0 * CDIM + kk * 64 + kb;
#pragma unroll
        for (int dc = 0; dc < 4; ++dc) {
            const float4 u = *reinterpret_cast<const float4*>(wk + (size_t)dc * CDIM);
            const float4 w = *reinterpret_cast<const float4*>(wk + (size_t)dc * CDIM + 4);
            bv[dc][0] = u.x; bv[dc][1] = u.y; bv[dc][2] = u.z; bv[dc][3] = u.w;
            bv[dc][4] = w.x; bv[dc][5] = w.y; bv[dc][6] = w.z; bv[dc][7] = w.w;
        }
    };

    auto write_tile = [&](int rb) {
#pragma unroll
        for (int dm = 0; dm < 4; ++dm) {           // A: transpose in regs
            const int row = sm0 + dm;
            bf16x8 w;
#pragma unroll
            for (int dk = 0; dk < 8; ++dk) w[dk] = (short)f2bf(av[rb][dk][dm]);
            *reinterpret_cast<bf16x8*>(ldsc + tswz(row, kb * 2)) = w;
        }
#pragma unroll
        for (int dc = 0; dc < 4; ++dc) {           // B: k already contiguous
            const int row = sm0 + dc;
            bf16x8 w;
#pragma unroll
            for (int dk = 0; dk < 8; ++dk) w[dk] = (short)f2bf(bv[dc][dk]);
            *reinterpret_cast<bf16x8*>(ldsc + 16384 + tswz(row, kb * 2)) = w;
        }
    };

    auto compute = [&]() {
#pragma unroll
        for (int ks = 0; ks < 2; ++ks) {
            const int kb2 = ks * 64 + ((lane >> 4) << 4);   // byte offset of k*2
            bf16x8 af[4], bfr[4];
#pragma unroll
            for (int mi = 0; mi < 4; ++mi) {
                const int row = wm * 64 + mi * 16 + (lane & 15);
                af[mi] = *reinterpret_cast<const bf16x8*>(ldsc + tswz(row, kb2));
            }
#pragma unroll
            for (int ni = 0; ni < 4; ++ni) {
                const int c = wn * 64 + ni * 16 + (lane & 15);
                bfr[ni] = *reinterpret_cast<const bf16x8*>(ldsc + 16384 + tswz(c, kb2));
            }
#pragma unroll
            for (int mi = 0; mi < 4; ++mi)
#pragma unroll
                for (int ni = 0; ni < 4; ++ni)
                    acc[mi][ni] = __builtin_amdgcn_mfma_f32_16x16x32_bf16(
                        af[mi], bfr[ni], acc[mi][ni], 0, 0, 0);
        }
    };

    // prologue: A(0),A(1) in flight; B(0); write tile 0
    load_a(0, 0);
    load_a(1, 1);
    load_b(0);
    write_tile(0);
    __syncthreads();
    // main loop: A(k+2) issued at top of step k (depth-2); B(k+1) depth-1
#pragma unroll
    for (int kk = 0; kk < 4; ++kk) {
        if (kk + 2 < 4) load_a(kk + 2, kk & 1);
        if (kk + 1 < 4) load_b(kk + 1);
        compute();
        __syncthreads();
        if (kk < 3) { write_tile((kk + 1) & 1); __syncthreads(); }
    }

    // ---- epilogue: acc -> bf16 -> LDS (swizzled) -> coalesced dwordx4 stores
#pragma unroll
    for (int mi = 0; mi < 4; ++mi)
#pragma unroll
        for (int ni = 0; ni < 4; ++ni) {
            const int c2 = (wn * 64 + ni * 16 + (lane & 15)) * 2;
#pragma unroll
            for (int r = 0; r < 4; ++r) {
                const int row = wm * 64 + mi * 16 + ((lane >> 4) << 2) + r;
                *reinterpret_cast<unsigned short*>(
                    ldsc + row * 256 + (c2 ^ (((row >> 2) & 3) << 5))) =
                    f2bf(acc[mi][ni][r]);
            }
        }
    __syncthreads();
#pragma unroll
    for (int i = 0; i < 8; ++i) {
        const int row = ((t >> 4) << 3) + i;
        const int cb  = (t & 15) * 16;
        const int4 v = *reinterpret_cast<const int4*>(
            ldsc + row * 256 + (cb ^ (((row >> 2) & 3) << 5)));
        *reinterpret_cast<int4*>((char*)f2t +
            (size_t)(m_base + row) * 512 + n_half * 256 + cb) = v;
    }
}

// 2 sample points per wave: 32 lanes/point, 8 channels/lane (16B bf16x8
// loads). Bilinear-weighted sum of 4 contiguous 512B F2t rows, then
// relu(s+b1).W2 -> 2 scalars; 5-step shfl_xor reduce within the 32-lane
// group; out = batch_edges + d.
__global__ __launch_bounds__(256) void point_kernel(
    const unsigned short* __restrict__ f2t,
    const float* __restrict__ be,
    const float* __restrict__ b1, const float* __restrict__ W2,
    float* __restrict__ out) {
    const int wave = (blockIdx.x << 2) | ((threadIdx.x >> 6) & 3);
    const int lane = threadIdx.x & 63;
    const int p    = (wave << 1) | (lane >> 5);     // 0..65535
    const int l5   = lane & 31;
    const int c0   = l5 << 3;                       // 8 channels per lane

    const float ex = be[p * 2 + 0];
    const float ey = be[p * 2 + 1];
    const float gx = ex * (2.0f / 128.0f) - 1.0f;
    const float gy = ey * (2.0f / 128.0f) - 1.0f;
    const float px = (gx + 1.0f) * 64.0f - 0.5f;
    const float py = (gy + 1.0f) * 64.0f - 0.5f;
    const float x0f = floorf(px), y0f = floorf(py);
    const int   x0 = (int)x0f, y0 = (int)y0f;
    const float wx1 = px - x0f, wy1 = py - y0f;
    const float wx0 = 1.0f - wx1, wy0 = 1.0f - wy1;

    const size_t pix_base = (size_t)(p >> 13) * HW;

    float s[8] = {};
#pragma unroll
    for (int cy = 0; cy < 2; ++cy) {
        const int   yi  = y0 + cy;
        const float wy  = cy ? wy1 : wy0;
        const bool  yin = (yi >= 0) && (yi < 128);
        const int   yc  = min(max(yi, 0), 127);
#pragma unroll
        for (int cx = 0; cx < 2; ++cx) {
            const int   xi  = x0 + cx;
            const float wx  = cx ? wx1 : wx0;
            const bool  xin = (xi >= 0) && (xi < 128);
            const int   xc  = min(max(xi, 0), 127);
            const float w   = wx * wy * (float)(xin && yin);
            const bf16x8 v = *reinterpret_cast<const bf16x8*>(
                &f2t[(pix_base + (size_t)yc * 128 + xc) * 256 + c0]);
#pragma unroll
            for (int j = 0; j < 8; ++j)
                s[j] += w * bf2f((unsigned short)v[j]);
        }
    }
    const float4 bb0 = *reinterpret_cast<const float4*>(&b1[c0]);
    const float4 bb1 = *reinterpret_cast<const float4*>(&b1[c0 + 4]);
    const float4 wa0 = *reinterpret_cast<const float4*>(&W2[c0]);
    const float4 wa1 = *reinterpret_cast<const float4*>(&W2[c0 + 4]);
    const float4 wb0 = *reinterpret_cast<const float4*>(&W2[256 + c0]);
    const float4 wb1 = *reinterpret_cast<const float4*>(&W2[256 + c0 + 4]);
    float bias[8] = {bb0.x, bb0.y, bb0.z, bb0.w, bb1.x, bb1.y, bb1.z, bb1.w};
    float w2a[8]  = {wa0.x, wa0.y, wa0.z, wa0.w, wa1.x, wa1.y, wa1.z, wa1.w};
    float w2b[8]  = {wb0.x, wb0.y, wb0.z, wb0.w, wb1.x, wb1.y, wb1.z, wb1.w};

    float a0 = 0.f, a1 = 0.f;
#pragma unroll
    for (int j = 0; j < 8; ++j) {
        const float h = fmaxf(s[j] + bias[j], 0.f);
        a0 += h * w2a[j];
        a1 += h * w2b[j];
    }
#pragma unroll
    for (int off = 16; off > 0; off >>= 1) {   // stays within 32-lane group
        a0 += __shfl_xor(a0, off);
        a1 += __shfl_xor(a1, off);
    }
    if (l5 == 0) {
        out[p * 2 + 0] = ex + a0;
        out[p * 2 + 1] = ey + a1;
    }
}

extern "C" void kernel_launch(void* const* d_in, const int* in_sizes, int n_in,
                              void* d_out, int out_size, void* d_ws, size_t ws_size,
                              hipStream_t stream) {
    const float* feat = (const float*)d_in[0];
    const float* be   = (const float*)d_in[1];
    const float* W1   = (const float*)d_in[2];
    const float* b1   = (const float*)d_in[3];
    const float* W2   = (const float*)d_in[4];
    float* out = (float*)d_out;
    unsigned short* f2t = (unsigned short*)d_ws;   // 131072*256 bf16 = 64 MiB

    f2_gemm<<<2048, 256, 0, stream>>>(feat, W1, f2t);
    point_kernel<<<8192, 256, 0, stream>>>(f2t, be, b1, W2, out);
}